// Round 2
// baseline (1052.900 us; speedup 1.0000x reference)
//
#include <hip/hip_runtime.h>
#include <hip/hip_bf16.h>
#include <stdint.h>

typedef __attribute__((ext_vector_type(8))) __bf16 bf16x8;
typedef __attribute__((ext_vector_type(4))) float f32x4;

static constexpr int kTokens = 8192;   // B*S = 4*2048
static constexpr int kHid    = 2048;   // H
static constexpr int kInter  = 8192;   // I
static constexpr int kN1     = 16384;  // 2*I, branch-interleaved in 16-col groups

// ---------------- async global->LDS 16B copy (global_load_lds_dwordx4) ----
// LDS dest is wave-uniform base + lane*16. Imm offset kept 0 (R3 note);
// all offsets via pointer arithmetic.
__device__ __forceinline__ void async16(const void* g, void* l) {
  using gp = const __attribute__((address_space(1))) unsigned int*;
  using lp = __attribute__((address_space(3))) unsigned int*;
  __builtin_amdgcn_global_load_lds((gp)(uintptr_t)g,
                                   (lp)(unsigned int)(uintptr_t)l, 16, 0, 0);
}

// ---------------- LayerNorm (f32 in) -> bf16 y --------------------------
__global__ __launch_bounds__(256) void ln_kernel(
    const float* __restrict__ x, const float* __restrict__ gamma,
    const float* __restrict__ beta, __hip_bfloat16* __restrict__ y) {
  const int t = threadIdx.x;
  const size_t row = blockIdx.x;
  const float* xr = x + row * kHid;
  float4 v0 = ((const float4*)xr)[2 * t];
  float4 v1 = ((const float4*)xr)[2 * t + 1];
  float s  = v0.x + v0.y + v0.z + v0.w + v1.x + v1.y + v1.z + v1.w;
  float s2 = v0.x*v0.x + v0.y*v0.y + v0.z*v0.z + v0.w*v0.w
           + v1.x*v1.x + v1.y*v1.y + v1.z*v1.z + v1.w*v1.w;
#pragma unroll
  for (int off = 1; off < 64; off <<= 1) {
    s  += __shfl_xor(s, off, 64);
    s2 += __shfl_xor(s2, off, 64);
  }
  __shared__ float red[8];
  const int w = t >> 6;
  if ((t & 63) == 0) { red[w] = s; red[4 + w] = s2; }
  __syncthreads();
  s  = red[0] + red[1] + red[2] + red[3];
  s2 = red[4] + red[5] + red[6] + red[7];
  const float mu = s * (1.0f / kHid);
  const float rs = rsqrtf(s2 * (1.0f / kHid) - mu * mu + 1e-6f);
  float4 g0 = ((const float4*)gamma)[2 * t], g1 = ((const float4*)gamma)[2 * t + 1];
  float4 b0 = ((const float4*)beta)[2 * t],  b1 = ((const float4*)beta)[2 * t + 1];
  union { __hip_bfloat16 h[8]; uint4 u; } pk;
  pk.h[0] = __float2bfloat16((v0.x - mu) * rs * g0.x + b0.x);
  pk.h[1] = __float2bfloat16((v0.y - mu) * rs * g0.y + b0.y);
  pk.h[2] = __float2bfloat16((v0.z - mu) * rs * g0.z + b0.z);
  pk.h[3] = __float2bfloat16((v0.w - mu) * rs * g0.w + b0.w);
  pk.h[4] = __float2bfloat16((v1.x - mu) * rs * g1.x + b1.x);
  pk.h[5] = __float2bfloat16((v1.y - mu) * rs * g1.y + b1.y);
  pk.h[6] = __float2bfloat16((v1.z - mu) * rs * g1.z + b1.z);
  pk.h[7] = __float2bfloat16((v1.w - mu) * rs * g1.w + b1.w);
  ((uint4*)(y + row * kHid))[t] = pk.u;
}

// ---------------- f32 (K x Ncols) -> bf16 transposed (N x K) -------------
template <bool INTERLEAVE>
__global__ __launch_bounds__(256) void cvt_tr(
    const float* __restrict__ src, __hip_bfloat16* __restrict__ dst,
    int K, int N) {
  __shared__ float tile[64][65];
  const int nb = blockIdx.x * 64;
  const int kb = blockIdx.y * 64;
  const int t = threadIdx.x;
#pragma unroll
  for (int it = 0; it < 16; ++it) {
    int p = t + it * 256;
    int lk = p >> 6, ln = p & 63;
    int n = nb + ln;
    int col = INTERLEAVE ? ((((n >> 4) & 1) << 13) + (((n >> 5) << 4) | (n & 15)))
                         : n;
    tile[lk][ln] = src[(size_t)(kb + lk) * N + col];
  }
  __syncthreads();
#pragma unroll
  for (int it = 0; it < 16; ++it) {
    int p = t + it * 256;
    int ln = p >> 6, lk = p & 63;
    dst[(size_t)(nb + ln) * K + kb + lk] = __float2bfloat16(tile[lk][ln]);
  }
}

// ---------------- 256x256 8-phase bf16 GEMM  C = A(MxK) * B^T(NxK) -------
// m201-template port: BK=64, 8 waves (2Mx4N), 512 thr, 2x64KB LDS dbuf in
// 4 half-tile slots each + 8KB dummy sink. XOR chunk swizzle (chunk ^= row&7):
// linear LDS dest, inverse-swizzled global source, swizzled ds_read.
//
// R1 stage ledger (deepened to vmcnt(8), loads aged >=4 phases at wait):
// Slot lifetimes from the actual read pattern (half-slot is selected by
// WAVE, not phase): buf.B halves both free after ph2/ph6, buf.A halves
// both free after ph3/ph7. Earliest stages:
//   ph3: t2.B (4 loads)   ph4: t2.A (4 loads) + vmcnt(8)  [t1 resident]
//   ph7: t3.B (4 loads)   ph8: t3.A (4 loads) + vmcnt(8)  [t2 resident]
// At each wait the awaited loads were issued 4-5 phases (~400 cyc) back.
// Out-of-range tail tiles stage dummies so vmcnt counts never change.
//
// Block decode is bx-major (by = wg&31, bx = wg>>5): the 32 concurrent
// blocks per XCD share ONE B column panel (GEMM1: 1MB, GEMM2: 4MB = L2),
// A streams from L3. Both grids are multiples of 8 (bijective XCD swizzle).
#define SLOT_A(b, h) ((b) * 65536 + (h) * 16384)
#define SLOT_B(b, h) ((b) * 65536 + 32768 + (h) * 16384)
#define SLOT_DUMMY 131072

template <int EPI>
__global__ __launch_bounds__(512, 2) void gemm8p(
    const __hip_bfloat16* __restrict__ A, const __hip_bfloat16* __restrict__ B,
    void* __restrict__ Cout, int M, int N, int K) {
  __shared__ __align__(16) char smem[139264];
  char* const sm = (char*)smem;

  const int t = threadIdx.x;
  const int lane = t & 63;
  const int wave = t >> 6;
  const int wm = wave >> 2;  // 0..1 (M waves)
  const int wn = wave & 3;   // 0..3 (N waves)

  // XCD-aware bijective swizzle (caller guarantees grid % 8 == 0)
  const int nwg = (int)gridDim.x;
  const int wg = ((int)blockIdx.x & 7) * (nwg >> 3) + ((int)blockIdx.x >> 3);
  const int by = wg & 31;        // M blocks (M = 8192 fixed)
  const int bx = wg >> 5;        // N blocks, bx-major per XCD
  const size_t m0 = (size_t)by * 256;
  const size_t n0 = (size_t)bx * 256;

  // staging lane constants: thread t writes linear LDS bytes t*16 (+8192);
  // row = t>>3 (+64 for 2nd load), stored chunk = t&7, source chunk XOR'd.
  const int srow = t >> 3;
  const int scsrc = (t & 7) ^ (srow & 7);
  const __hip_bfloat16* const gA = A + (m0 + srow) * K + scsrc * 8;
  const __hip_bfloat16* const gB = B + (n0 + srow) * K + scsrc * 8;
  const size_t K64  = (size_t)64 * K;
  const size_t K128 = (size_t)128 * K;
  const int t16 = t * 16;
  char* const dm = sm + SLOT_DUMMY + t16;

  // fragment-read lane constants (row&7 == col&7 for all frag rows)
  const int col = lane & 15, q = lane >> 4;
  const int cs0 = (q ^ (col & 7)) * 16;        // kk=0 stored chunk
  const int cs1 = ((4 + q) ^ (col & 7)) * 16;  // kk=1
  const int aO0 = wm * 16384 + col * 128 + cs0;
  const int aO1 = wm * 16384 + col * 128 + cs1;
  const int bO0 = 32768 + (wn >> 1) * 16384 + ((wn & 1) * 64 + col) * 128 + cs0;
  const int bO1 = 32768 + (wn >> 1) * 16384 + ((wn & 1) * 64 + col) * 128 + cs1;

  f32x4 acc[8][4] = {};
  bf16x8 af[4][2], bf[4][2];

  const int NT = K >> 6;  // 64-wide K tiles (even for both GEMMs)
  const int L  = NT >> 1; // 2 tiles per iteration

  // stage a full A half-pair (both 16KB halves, 4 loads) into buf
#define STG_A2(tile, buf)                                \
  do {                                                   \
    const __hip_bfloat16* _s = gA + (size_t)(tile) * 64; \
    char* _d = sm + SLOT_A(buf, 0) + t16;                \
    async16(_s, _d);                                     \
    async16(_s + K64, _d + 8192);                        \
    async16(_s + K128, _d + 16384);                      \
    async16(_s + K128 + K64, _d + 16384 + 8192);         \
  } while (0)
#define STG_B2(tile, buf)                                \
  do {                                                   \
    const __hip_bfloat16* _s = gB + (size_t)(tile) * 64; \
    char* _d = sm + SLOT_B(buf, 0) + t16;                \
    async16(_s, _d);                                     \
    async16(_s + K64, _d + 8192);                        \
    async16(_s + K128, _d + 16384);                      \
    async16(_s + K128 + K64, _d + 16384 + 8192);         \
  } while (0)
#define STG_A2_G(tile, buf)                              \
  do {                                                   \
    if ((tile) < NT) { STG_A2(tile, buf); }              \
    else { async16(A, dm); async16(A, dm);               \
           async16(A, dm); async16(A, dm); }             \
  } while (0)
#define STG_B2_G(tile, buf)                              \
  do {                                                   \
    if ((tile) < NT) { STG_B2(tile, buf); }              \
    else { async16(A, dm); async16(A, dm);               \
           async16(A, dm); async16(A, dm); }             \
  } while (0)

#define LOAD_A(buf, mh)                                                        \
  { _Pragma("unroll") for (int ii = 0; ii < 4; ++ii) {                         \
      af[ii][0] = *(const bf16x8*)(sm + (buf)*65536 + aO0 + (mh)*8192 + ii*2048); \
      af[ii][1] = *(const bf16x8*)(sm + (buf)*65536 + aO1 + (mh)*8192 + ii*2048); \
  } }
#define LOAD_B(buf, nh)                                                        \
  { _Pragma("unroll") for (int jj = 0; jj < 2; ++jj) {                         \
      bf[(nh)*2 + jj][0] = *(const bf16x8*)(sm + (buf)*65536 + bO0 + ((nh)*2 + jj)*2048); \
      bf[(nh)*2 + jj][1] = *(const bf16x8*)(sm + (buf)*65536 + bO1 + ((nh)*2 + jj)*2048); \
  } }

#define MFMA_QUAD(mh, nh)                                                     \
  { _Pragma("unroll") for (int kk = 0; kk < 2; ++kk)                          \
    _Pragma("unroll") for (int ii = 0; ii < 4; ++ii)                          \
    _Pragma("unroll") for (int jj = 0; jj < 2; ++jj)                          \
      acc[(mh)*4 + ii][(nh)*2 + jj] = __builtin_amdgcn_mfma_f32_16x16x32_bf16( \
          af[ii][kk], bf[(nh)*2 + jj][kk], acc[(mh)*4 + ii][(nh)*2 + jj], 0, 0, 0); }

#define PHASE_MID()                                  \
  __builtin_amdgcn_s_barrier();                      \
  asm volatile("s_waitcnt lgkmcnt(0)" ::: "memory"); \
  __builtin_amdgcn_s_setprio(1)
  // 12-ds_read phases: partial drain before barrier (m201 optional hint)
#define PHASE_MID12()                                \
  asm volatile("s_waitcnt lgkmcnt(8)" ::: "memory"); \
  __builtin_amdgcn_s_barrier();                      \
  asm volatile("s_waitcnt lgkmcnt(0)" ::: "memory"); \
  __builtin_amdgcn_s_setprio(1)
#define PHASE_MID_VM()                               \
  asm volatile("s_waitcnt vmcnt(8)" ::: "memory");   \
  __builtin_amdgcn_s_barrier();                      \
  asm volatile("s_waitcnt lgkmcnt(0)" ::: "memory"); \
  __builtin_amdgcn_s_setprio(1)
#define PHASE_END()                                  \
  __builtin_amdgcn_s_setprio(0);                     \
  __builtin_amdgcn_s_barrier()

  // prologue: tile0 + tile1 fully staged (16 loads); wait leaves tile1's
  // 8 loads in flight -> identical ledger state to loop steady-state.
  STG_B2(0, 0);
  STG_A2(0, 0);
  STG_B2(1, 1);
  STG_A2(1, 1);
  asm volatile("s_waitcnt vmcnt(8)" ::: "memory");
  __builtin_amdgcn_s_barrier();

#pragma unroll 1
  for (int i = 0; i < L; ++i) {
    const int t2 = 2 * i + 2, t3 = 2 * i + 3;
    // ph1: tile 2i (buf0) quad(0,0)
    LOAD_A(0, 0) LOAD_B(0, 0)
    PHASE_MID12(); MFMA_QUAD(0, 0) PHASE_END();
    // ph2: quad(0,1) — B halves free after this phase
    LOAD_B(0, 1)
    PHASE_MID(); MFMA_QUAD(0, 1) PHASE_END();
    // ph3: quad(1,0) — stage t2.B; A halves free after this phase
    LOAD_A(0, 1)
    STG_B2_G(t2, 0);
    PHASE_MID(); MFMA_QUAD(1, 0) PHASE_END();
    // ph4: quad(1,1) — stage t2.A; counted vmcnt(8) -> tile 2i+1 resident
    STG_A2_G(t2, 0);
    PHASE_MID_VM(); MFMA_QUAD(1, 1) PHASE_END();
    // ph5: tile 2i+1 (buf1) quad(0,0)
    LOAD_A(1, 0) LOAD_B(1, 0)
    PHASE_MID12(); MFMA_QUAD(0, 0) PHASE_END();
    // ph6: quad(0,1)
    LOAD_B(1, 1)
    PHASE_MID(); MFMA_QUAD(0, 1) PHASE_END();
    // ph7: quad(1,0) — stage t3.B
    LOAD_A(1, 1)
    STG_B2_G(t3, 1);
    PHASE_MID(); MFMA_QUAD(1, 0) PHASE_END();
    // ph8: quad(1,1) — stage t3.A; counted vmcnt(8) -> tile 2i+2 resident
    STG_A2_G(t3, 1);
    PHASE_MID_VM(); MFMA_QUAD(1, 1) PHASE_END();
  }
  asm volatile("s_waitcnt vmcnt(0)" ::: "memory");  // drain before LDS dealloc

  // C/D layout: col = lane&15, row = (lane>>4)*4 + reg   [m89-verified]
  const int gr0 = (int)m0 + wm * 128 + q * 4;
  if (EPI == 0) {
    float* Cf = (float*)Cout;
    const int gc0 = (int)n0 + wn * 64 + col;
#pragma unroll
    for (int mi = 0; mi < 8; ++mi)
#pragma unroll
      for (int j = 0; j < 4; ++j) {
        size_t base = (size_t)(gr0 + mi * 16) * N + gc0 + j * 16;
#pragma unroll
        for (int r = 0; r < 4; ++r) Cf[base + (size_t)r * N] = acc[mi][j][r];
      }
  } else {
    __hip_bfloat16* Z = (__hip_bfloat16*)Cout;
    const int ldz = N >> 1;
    const size_t ib0 = (n0 >> 1) + wn * 32 + col;
#pragma unroll
    for (int mi = 0; mi < 8; ++mi)
#pragma unroll
      for (int tp = 0; tp < 2; ++tp) {
        const f32x4 gg = acc[mi][2 * tp];      // gate (a=0) 16-col tile
        const f32x4 ll = acc[mi][2 * tp + 1];  // linear (a=1) 16-col tile
        size_t base = (size_t)(gr0 + mi * 16) * ldz + ib0 + tp * 16;
#pragma unroll
        for (int r = 0; r < 4; ++r) {
          // gelu_tanh(x) = x * sigmoid(2u), u = 0.79788456*(x + 0.044715 x^3)
          float xv = gg[r];
          float u = 0.7978845608028654f * xv * (1.0f + 0.044715f * xv * xv);
          float sg = __builtin_amdgcn_rcpf(1.0f + __expf(-2.0f * u));
          Z[base + (size_t)r * ldz] = __float2bfloat16(xv * sg * ll[r]);
        }
      }
  }
}

extern "C" void kernel_launch(void* const* d_in, const int* in_sizes, int n_in,
                              void* d_out, int out_size, void* d_ws, size_t ws_size,
                              hipStream_t stream) {
  const float* x     = (const float*)d_in[0];
  const float* gamma = (const float*)d_in[1];
  const float* beta  = (const float*)d_in[2];
  const float* W1    = (const float*)d_in[3];  // [H, 2, I] f32
  const float* W2    = (const float*)d_in[4];  // [I, H] f32
  float* out = (float*)d_out;

  char* ws = (char*)d_ws;
  __hip_bfloat16* yb  = (__hip_bfloat16*)ws;                    // 32 MB
  __hip_bfloat16* w1t = (__hip_bfloat16*)(ws + (32ull << 20));  // 64 MB
  __hip_bfloat16* w2t = (__hip_bfloat16*)(ws + (96ull << 20));  // 32 MB
  __hip_bfloat16* z   = (__hip_bfloat16*)(ws + (128ull << 20)); // 128 MB
  (void)in_sizes; (void)n_in; (void)out_size; (void)ws_size;

  ln_kernel<<<kTokens, 256, 0, stream>>>(x, gamma, beta, yb);
  cvt_tr<true ><<<dim3(kN1 / 64, kHid / 64), 256, 0, stream>>>(W1, w1t, kHid, kN1);
  cvt_tr<false><<<dim3(kHid / 64, kInter / 64), 256, 0, stream>>>(W2, w2t, kInter, kHid);
  // GEMM1: M=8192, N=16384, K=2048 -> grid 64*32 = 2048
  gemm8p<1><<<dim3((kN1 / 256) * (kTokens / 256)), 512, 0, stream>>>(
      yb, w1t, (void*)z, kTokens, kN1, kHid);
  // GEMM2: M=8192, N=2048, K=8192 -> grid 8*32 = 256
  gemm8p<0><<<dim3((kHid / 256) * (kTokens / 256)), 512, 0, stream>>>(
      z, w2t, (void*)out, kTokens, kHid, kInter);
}

// Round 3
// 975.306 us; speedup vs baseline: 1.0796x; 1.0796x over previous
//
#include <hip/hip_runtime.h>
#include <hip/hip_bf16.h>
#include <stdint.h>

typedef __attribute__((ext_vector_type(8))) __bf16 bf16x8;
typedef __attribute__((ext_vector_type(4))) float f32x4;

static constexpr int kTokens = 8192;   // B*S = 4*2048
static constexpr int kHid    = 2048;   // H
static constexpr int kInter  = 8192;   // I
static constexpr int kN1     = 16384;  // 2*I, branch-interleaved in 16-col groups

// ---------------- async global->LDS 16B copy (global_load_lds_dwordx4) ----
// LDS dest is wave-uniform base + lane*16. Imm offset kept 0 (R3 note);
// all offsets via pointer arithmetic.
__device__ __forceinline__ void async16(const void* g, void* l) {
  using gp = const __attribute__((address_space(1))) unsigned int*;
  using lp = __attribute__((address_space(3))) unsigned int*;
  __builtin_amdgcn_global_load_lds((gp)(uintptr_t)g,
                                   (lp)(unsigned int)(uintptr_t)l, 16, 0, 0);
}

// ---------------- LayerNorm (f32 in) -> bf16 y --------------------------
__global__ __launch_bounds__(256) void ln_kernel(
    const float* __restrict__ x, const float* __restrict__ gamma,
    const float* __restrict__ beta, __hip_bfloat16* __restrict__ y) {
  const int t = threadIdx.x;
  const size_t row = blockIdx.x;
  const float* xr = x + row * kHid;
  float4 v0 = ((const float4*)xr)[2 * t];
  float4 v1 = ((const float4*)xr)[2 * t + 1];
  float s  = v0.x + v0.y + v0.z + v0.w + v1.x + v1.y + v1.z + v1.w;
  float s2 = v0.x*v0.x + v0.y*v0.y + v0.z*v0.z + v0.w*v0.w
           + v1.x*v1.x + v1.y*v1.y + v1.z*v1.z + v1.w*v1.w;
#pragma unroll
  for (int off = 1; off < 64; off <<= 1) {
    s  += __shfl_xor(s, off, 64);
    s2 += __shfl_xor(s2, off, 64);
  }
  __shared__ float red[8];
  const int w = t >> 6;
  if ((t & 63) == 0) { red[w] = s; red[4 + w] = s2; }
  __syncthreads();
  s  = red[0] + red[1] + red[2] + red[3];
  s2 = red[4] + red[5] + red[6] + red[7];
  const float mu = s * (1.0f / kHid);
  const float rs = rsqrtf(s2 * (1.0f / kHid) - mu * mu + 1e-6f);
  float4 g0 = ((const float4*)gamma)[2 * t], g1 = ((const float4*)gamma)[2 * t + 1];
  float4 b0 = ((const float4*)beta)[2 * t],  b1 = ((const float4*)beta)[2 * t + 1];
  union { __hip_bfloat16 h[8]; uint4 u; } pk;
  pk.h[0] = __float2bfloat16((v0.x - mu) * rs * g0.x + b0.x);
  pk.h[1] = __float2bfloat16((v0.y - mu) * rs * g0.y + b0.y);
  pk.h[2] = __float2bfloat16((v0.z - mu) * rs * g0.z + b0.z);
  pk.h[3] = __float2bfloat16((v0.w - mu) * rs * g0.w + b0.w);
  pk.h[4] = __float2bfloat16((v1.x - mu) * rs * g1.x + b1.x);
  pk.h[5] = __float2bfloat16((v1.y - mu) * rs * g1.y + b1.y);
  pk.h[6] = __float2bfloat16((v1.z - mu) * rs * g1.z + b1.z);
  pk.h[7] = __float2bfloat16((v1.w - mu) * rs * g1.w + b1.w);
  ((uint4*)(y + row * kHid))[t] = pk.u;
}

// ---------------- f32 (K x Ncols) -> bf16 transposed (N x K) -------------
template <bool INTERLEAVE>
__global__ __launch_bounds__(256) void cvt_tr(
    const float* __restrict__ src, __hip_bfloat16* __restrict__ dst,
    int K, int N) {
  __shared__ float tile[64][65];
  const int nb = blockIdx.x * 64;
  const int kb = blockIdx.y * 64;
  const int t = threadIdx.x;
#pragma unroll
  for (int it = 0; it < 16; ++it) {
    int p = t + it * 256;
    int lk = p >> 6, ln = p & 63;
    int n = nb + ln;
    int col = INTERLEAVE ? ((((n >> 4) & 1) << 13) + (((n >> 5) << 4) | (n & 15)))
                         : n;
    tile[lk][ln] = src[(size_t)(kb + lk) * N + col];
  }
  __syncthreads();
#pragma unroll
  for (int it = 0; it < 16; ++it) {
    int p = t + it * 256;
    int ln = p >> 6, lk = p & 63;
    dst[(size_t)(nb + ln) * K + kb + lk] = __float2bfloat16(tile[lk][ln]);
  }
}

// ---------------- 256x256 8-phase bf16 GEMM  C = A(MxK) * B^T(NxK) -------
// m201-template port: BK=64, 8 waves (2Mx4N), 512 thr, 2x64KB LDS dbuf in
// 4 half-tile slots each + 8KB dummy sink. Counted vmcnt(4) at phases 4/8
// only (2 half-tiles in flight across barriers). XOR chunk swizzle
// (chunk ^= row&7): linear LDS dest, inverse-swizzled global source,
// swizzled ds_read -> even 8-way bank-group spread.
// Stage ledger (iter i) [R0, proven]: ph1:(2i+1).A0  ph2:(2i+1).A1
// ph3:(2i+2).B0  ph4:(2i+2).B1+VM  ph5:(2i+2).A0  ph6:(2i+2).A1
// ph7:(2i+3).B0  ph8:(2i+3).B1+VM.  Slot last-reads precede restage by
// >=1 barrier pair -> no restage race. Tail tiles stage dummies so vmcnt
// counts never change.
// R2 delta: ds_read rebalance 12/4/8/0 -> 8/4/8/4 (m201's "4 or 8"):
// each bfN0 4-read group issues inside the PRIOR phase's MFMA region,
// after PHASE_MID_VM's vmcnt+barrier (residency collective there). No WAR:
// ph4/ph8 MFMA consume bf[2..3] while early reads fill bf[0..1]; zero
// extra registers. A-groups stay pre-barrier (2nd af set would exceed the
// 128 VGPR + 128 AGPR budget at 8 waves/CU).
#define SLOT_A(b, h) ((b) * 65536 + (h) * 16384)
#define SLOT_B(b, h) ((b) * 65536 + 32768 + (h) * 16384)
#define SLOT_DUMMY 131072

template <int EPI, int NXTLOG>
__global__ __launch_bounds__(512, 2) void gemm8p(
    const __hip_bfloat16* __restrict__ A, const __hip_bfloat16* __restrict__ B,
    void* __restrict__ Cout, int M, int N, int K) {
  __shared__ __align__(16) char smem[139264];
  char* const sm = (char*)smem;

  const int t = threadIdx.x;
  const int lane = t & 63;
  const int wave = t >> 6;
  const int wm = wave >> 2;  // 0..1 (M waves)
  const int wn = wave & 3;   // 0..3 (N waves)

  // XCD-aware bijective swizzle (caller guarantees grid % 8 == 0)
  const int nwg = (int)gridDim.x;
  const int wg = ((int)blockIdx.x & 7) * (nwg >> 3) + ((int)blockIdx.x >> 3);
  const int bx = wg & ((1 << NXTLOG) - 1);
  const int by = wg >> NXTLOG;
  const size_t m0 = (size_t)by * 256;
  const size_t n0 = (size_t)bx * 256;

  // staging lane constants: thread t writes linear LDS bytes t*16 (+8192);
  // row = t>>3 (+64 for 2nd load), stored chunk = t&7, source chunk XOR'd.
  const int srow = t >> 3;
  const int scsrc = (t & 7) ^ (srow & 7);
  const __hip_bfloat16* const gA = A + (m0 + srow) * K + scsrc * 8;
  const __hip_bfloat16* const gB = B + (n0 + srow) * K + scsrc * 8;
  const size_t K64  = (size_t)64 * K;
  const size_t K128 = (size_t)128 * K;
  const int t16 = t * 16;
  char* const dm = sm + SLOT_DUMMY + t16;

  // fragment-read lane constants (row&7 == col&7 for all frag rows)
  const int col = lane & 15, q = lane >> 4;
  const int cs0 = (q ^ (col & 7)) * 16;        // kk=0 stored chunk
  const int cs1 = ((4 + q) ^ (col & 7)) * 16;  // kk=1
  const int aO0 = wm * 16384 + col * 128 + cs0;
  const int aO1 = wm * 16384 + col * 128 + cs1;
  const int bO0 = 32768 + (wn >> 1) * 16384 + ((wn & 1) * 64 + col) * 128 + cs0;
  const int bO1 = 32768 + (wn >> 1) * 16384 + ((wn & 1) * 64 + col) * 128 + cs1;

  f32x4 acc[8][4] = {};
  bf16x8 af[4][2], bf[4][2];

  const int NT = K >> 6;  // 64-wide K tiles (even for both GEMMs)
  const int L  = NT >> 1; // 2 tiles per iteration

#define STG_A(tile, h, buf)                                           \
  do {                                                                \
    const __hip_bfloat16* _s = gA + (size_t)(tile) * 64 + (h) * K128; \
    char* _d = sm + SLOT_A(buf, h) + t16;                             \
    async16(_s, _d);                                                  \
    async16(_s + K64, _d + 8192);                                     \
  } while (0)
#define STG_B(tile, h, buf)                                           \
  do {                                                                \
    const __hip_bfloat16* _s = gB + (size_t)(tile) * 64 + (h) * K128; \
    char* _d = sm + SLOT_B(buf, h) + t16;                             \
    async16(_s, _d);                                                  \
    async16(_s + K64, _d + 8192);                                     \
  } while (0)
#define STG_A_G(tile, h, buf)                  \
  do {                                         \
    if ((tile) < NT) { STG_A(tile, h, buf); }  \
    else { async16(A, dm); async16(A, dm); }   \
  } while (0)
#define STG_B_G(tile, h, buf)                  \
  do {                                         \
    if ((tile) < NT) { STG_B(tile, h, buf); }  \
    else { async16(A, dm); async16(A, dm); }   \
  } while (0)

#define LOAD_A(buf, mh)                                                        \
  { _Pragma("unroll") for (int ii = 0; ii < 4; ++ii) {                         \
      af[ii][0] = *(const bf16x8*)(sm + (buf)*65536 + aO0 + (mh)*8192 + ii*2048); \
      af[ii][1] = *(const bf16x8*)(sm + (buf)*65536 + aO1 + (mh)*8192 + ii*2048); \
  } }
#define LOAD_B(buf, nh)                                                        \
  { _Pragma("unroll") for (int jj = 0; jj < 2; ++jj) {                         \
      bf[(nh)*2 + jj][0] = *(const bf16x8*)(sm + (buf)*65536 + bO0 + ((nh)*2 + jj)*2048); \
      bf[(nh)*2 + jj][1] = *(const bf16x8*)(sm + (buf)*65536 + bO1 + ((nh)*2 + jj)*2048); \
  } }

#define MFMA_QUAD(mh, nh)                                                     \
  { _Pragma("unroll") for (int kk = 0; kk < 2; ++kk)                          \
    _Pragma("unroll") for (int ii = 0; ii < 4; ++ii)                          \
    _Pragma("unroll") for (int jj = 0; jj < 2; ++jj)                          \
      acc[(mh)*4 + ii][(nh)*2 + jj] = __builtin_amdgcn_mfma_f32_16x16x32_bf16( \
          af[ii][kk], bf[(nh)*2 + jj][kk], acc[(mh)*4 + ii][(nh)*2 + jj], 0, 0, 0); }

#define PHASE_MID()                                  \
  __builtin_amdgcn_s_barrier();                      \
  asm volatile("s_waitcnt lgkmcnt(0)" ::: "memory"); \
  __builtin_amdgcn_s_setprio(1)
#define PHASE_MID_VM()                               \
  asm volatile("s_waitcnt vmcnt(4)" ::: "memory");   \
  __builtin_amdgcn_s_barrier();                      \
  asm volatile("s_waitcnt lgkmcnt(0)" ::: "memory"); \
  __builtin_amdgcn_s_setprio(1)
#define PHASE_END()                                  \
  __builtin_amdgcn_s_setprio(0);                     \
  __builtin_amdgcn_s_barrier()

  // prologue: tile0 {A0,A1,B0,B1} + tile1 {B0,B1}; wait leaves tile1.B in
  // flight. Then pre-issue bfN0(tile0) (loop-carried: ph8 feeds ph1).
  STG_A(0, 0, 0);
  STG_A(0, 1, 0);
  STG_B(0, 0, 0);
  STG_B(0, 1, 0);
  STG_B(1, 0, 1);
  STG_B(1, 1, 1);
  asm volatile("s_waitcnt vmcnt(4)" ::: "memory");
  __builtin_amdgcn_s_barrier();
  LOAD_B(0, 0)

#pragma unroll 1
  for (int i = 0; i < L; ++i) {
    const int t1 = 2 * i + 1, t2 = 2 * i + 2, t3 = 2 * i + 3;
    // ph1: tile 2i (buf0) quad(0,0) — bf[0..1] already in flight from ph8
    LOAD_A(0, 0)
    STG_A(t1, 0, 1);
    PHASE_MID(); MFMA_QUAD(0, 0) PHASE_END();
    // ph2: quad(0,1)
    LOAD_B(0, 1)
    STG_A(t1, 1, 1);
    PHASE_MID(); MFMA_QUAD(0, 1) PHASE_END();
    // ph3: quad(1,0)
    LOAD_A(0, 1)
    STG_B_G(t2, 0, 0);
    PHASE_MID(); MFMA_QUAD(1, 0) PHASE_END();
    // ph4: quad(1,1); vmcnt(4) -> tile 2i+1 resident; early-issue bfN0(buf1)
    // inside MFMA region (reads fill bf[0..1], MFMA uses bf[2..3])
    STG_B_G(t2, 1, 0);
    PHASE_MID_VM();
    LOAD_B(1, 0)
    MFMA_QUAD(1, 1) PHASE_END();
    // ph5: tile 2i+1 (buf1) quad(0,0)
    LOAD_A(1, 0)
    STG_A_G(t2, 0, 0);
    PHASE_MID(); MFMA_QUAD(0, 0) PHASE_END();
    // ph6: quad(0,1)
    LOAD_B(1, 1)
    STG_A_G(t2, 1, 0);
    PHASE_MID(); MFMA_QUAD(0, 1) PHASE_END();
    // ph7: quad(1,0)
    LOAD_A(1, 1)
    STG_B_G(t3, 0, 1);
    PHASE_MID(); MFMA_QUAD(1, 0) PHASE_END();
    // ph8: quad(1,1); vmcnt(4) -> tile 2i+2 resident; early-issue bfN0(buf0)
    // for next iteration's ph1 (harmless garbage read on final iteration)
    STG_B_G(t3, 1, 1);
    PHASE_MID_VM();
    LOAD_B(0, 0)
    MFMA_QUAD(1, 1) PHASE_END();
  }
  asm volatile("s_waitcnt vmcnt(0)" ::: "memory");  // drain before LDS dealloc

  // C/D layout: col = lane&15, row = (lane>>4)*4 + reg   [m89-verified]
  const int gr0 = (int)m0 + wm * 128 + q * 4;
  if (EPI == 0) {
    float* Cf = (float*)Cout;
    const int gc0 = (int)n0 + wn * 64 + col;
#pragma unroll
    for (int mi = 0; mi < 8; ++mi)
#pragma unroll
      for (int j = 0; j < 4; ++j) {
        size_t base = (size_t)(gr0 + mi * 16) * N + gc0 + j * 16;
#pragma unroll
        for (int r = 0; r < 4; ++r) Cf[base + (size_t)r * N] = acc[mi][j][r];
      }
  } else {
    __hip_bfloat16* Z = (__hip_bfloat16*)Cout;
    const int ldz = N >> 1;
    const size_t ib0 = (n0 >> 1) + wn * 32 + col;
#pragma unroll
    for (int mi = 0; mi < 8; ++mi)
#pragma unroll
      for (int tp = 0; tp < 2; ++tp) {
        const f32x4 gg = acc[mi][2 * tp];      // gate (a=0) 16-col tile
        const f32x4 ll = acc[mi][2 * tp + 1];  // linear (a=1) 16-col tile
        size_t base = (size_t)(gr0 + mi * 16) * ldz + ib0 + tp * 16;
#pragma unroll
        for (int r = 0; r < 4; ++r) {
          // gelu_tanh(x) = x * sigmoid(2u), u = 0.79788456*(x + 0.044715 x^3)
          float xv = gg[r];
          float u = 0.7978845608028654f * xv * (1.0f + 0.044715f * xv * xv);
          float sg = __builtin_amdgcn_rcpf(1.0f + __expf(-2.0f * u));
          Z[base + (size_t)r * ldz] = __float2bfloat16(xv * sg * ll[r]);
        }
      }
  }
}

extern "C" void kernel_launch(void* const* d_in, const int* in_sizes, int n_in,
                              void* d_out, int out_size, void* d_ws, size_t ws_size,
                              hipStream_t stream) {
  const float* x     = (const float*)d_in[0];
  const float* gamma = (const float*)d_in[1];
  const float* beta  = (const float*)d_in[2];
  const float* W1    = (const float*)d_in[3];  // [H, 2, I] f32
  const float* W2    = (const float*)d_in[4];  // [I, H] f32
  float* out = (float*)d_out;

  char* ws = (char*)d_ws;
  __hip_bfloat16* yb  = (__hip_bfloat16*)ws;                    // 32 MB
  __hip_bfloat16* w1t = (__hip_bfloat16*)(ws + (32ull << 20));  // 64 MB
  __hip_bfloat16* w2t = (__hip_bfloat16*)(ws + (96ull << 20));  // 32 MB
  __hip_bfloat16* z   = (__hip_bfloat16*)(ws + (128ull << 20)); // 128 MB
  (void)in_sizes; (void)n_in; (void)out_size; (void)ws_size;

  ln_kernel<<<kTokens, 256, 0, stream>>>(x, gamma, beta, yb);
  cvt_tr<true ><<<dim3(kN1 / 64, kHid / 64), 256, 0, stream>>>(W1, w1t, kHid, kN1);
  cvt_tr<false><<<dim3(kHid / 64, kInter / 64), 256, 0, stream>>>(W2, w2t, kInter, kHid);
  // GEMM1: M=8192, N=16384, K=2048 -> grid 64*32 = 2048 (NXT=64 -> log 6)
  gemm8p<1, 6><<<dim3((kN1 / 256) * (kTokens / 256)), 512, 0, stream>>>(
      yb, w1t, (void*)z, kTokens, kN1, kHid);
  // GEMM2: M=8192, N=2048, K=8192 -> grid 8*32 = 256 (NXT=8 -> log 3)
  gemm8p<0, 3><<<dim3((kHid / 256) * (kTokens / 256)), 512, 0, stream>>>(
      z, w2t, (void*)out, kTokens, kHid, kInter);
}